// Round 3
// baseline (145.740 us; speedup 1.0000x reference)
//
#include <hip/hip_runtime.h>
#include <math.h>

// SinkhornM round 3:
//  - R=4 rows/thread to halve LDS-pipe pressure (weight broadcasts amortize
//    over 4 rows: ~65 ds_read/row vs 114 in round 2).
//  - Layer 1 restructured output-stationary: compute h1[j] (8 FMAs/row from
//    transposed W1 row), ReLU, immediately scatter into h2 accumulators via
//    W2 row j, then h1[j] dies. Kills the h1[R][32] live range -> R=4 fits
//    in ~120 VGPRs (4 waves/SIMD).
//  - Same math as round 2 otherwise (u/v-form Sinkhorn, W3 transposed).

#define EPS_F 1e-12f
#define QLOW  0.02f
#define QSPAN 0.96f

constexpr int R = 4;

__device__ __forceinline__ float frcp(float x) { return __builtin_amdgcn_rcpf(x); }
__device__ __forceinline__ float fsig(float x) { return frcp(1.0f + __expf(-x)); }

__global__ __launch_bounds__(256) void sinkhorn_fused(
    const float* __restrict__ margins,
    const float* __restrict__ W1, const float* __restrict__ b1,
    const float* __restrict__ W2, const float* __restrict__ b2,
    const float* __restrict__ W3, const float* __restrict__ b3,
    float* __restrict__ out, int n)
{
    // ---- LDS staging ----
    __shared__ __align__(16) float sW1T[256];  // (32,8): sW1T[j*8+k] = W1[k*32+j]
    __shared__ __align__(16) float sW2[512];   // (32,16) row-major
    __shared__ __align__(16) float sW3T[144];  // (9,16):  sW3T[j*16+k] = W3[k*9+j]
    __shared__ __align__(16) float sB1[32];
    __shared__ __align__(16) float sB2[16];
    __shared__ __align__(16) float sB3[12];

    {
        const int t = threadIdx.x;
        { const int j = t >> 3, k = t & 7; sW1T[t] = W1[k * 32 + j]; }
        sW2[t] = W2[t];
        sW2[t + 256] = W2[t + 256];
        if (t < 144) { const int k = t / 9, j = t - 9 * k; sW3T[j * 16 + k] = W3[t]; }
        if (t < 32) sB1[t] = b1[t];
        if (t < 16) sB2[t] = b2[t];
        if (t < 9)  sB3[t] = b3[t];
    }
    __syncthreads();

    const float4* __restrict__ sW1Tv = (const float4*)sW1T;
    const float4* __restrict__ sW2v  = (const float4*)sW2;
    const float4* __restrict__ sW3Tv = (const float4*)sW3T;

    const int tid  = blockIdx.x * blockDim.x + threadIdx.x;
    const int lane = tid & 63;
    const int base = (tid >> 6) * (64 * R) + lane;  // rows base + 64*r

    const float4* __restrict__ m4 = (const float4*)margins;

    // ---- margins ----
    float m[R][8];
#pragma unroll
    for (int r = 0; r < R; ++r) {
        const int row = base + 64 * r;
        const float4 a0 = m4[row * 2 + 0];
        const float4 a1 = m4[row * 2 + 1];
        m[r][0] = a0.x; m[r][1] = a0.y; m[r][2] = a0.z; m[r][3] = a0.w;
        m[r][4] = a1.x; m[r][5] = a1.y; m[r][6] = a1.z; m[r][7] = a1.w;
    }

    // ---- h2 accumulators, init with bias ----
    float h2[R][16];
#pragma unroll
    for (int j = 0; j < 16; ++j) {
        const float bb = sB2[j];
#pragma unroll
        for (int r = 0; r < R; ++r) h2[r][j] = bb;
    }

    // ---- fused layer1+layer2: output-stationary over h1[j] ----
#pragma unroll
    for (int j = 0; j < 32; ++j) {
        const float4 wa = sW1Tv[j * 2 + 0];   // W1[0..3][j]
        const float4 wb = sW1Tv[j * 2 + 1];   // W1[4..7][j]
        const float bj = sB1[j];
        float h[R];
#pragma unroll
        for (int r = 0; r < R; ++r) {
            float x = bj;
            x = fmaf(m[r][0], wa.x, x);
            x = fmaf(m[r][1], wa.y, x);
            x = fmaf(m[r][2], wa.z, x);
            x = fmaf(m[r][3], wa.w, x);
            x = fmaf(m[r][4], wb.x, x);
            x = fmaf(m[r][5], wb.y, x);
            x = fmaf(m[r][6], wb.z, x);
            x = fmaf(m[r][7], wb.w, x);
            h[r] = fmaxf(x, 0.0f);
        }
#pragma unroll
        for (int j4 = 0; j4 < 4; ++j4) {
            const float4 w = sW2v[j * 4 + j4];
#pragma unroll
            for (int r = 0; r < R; ++r) {
                h2[r][j4*4+0] = fmaf(h[r], w.x, h2[r][j4*4+0]);
                h2[r][j4*4+1] = fmaf(h[r], w.y, h2[r][j4*4+1]);
                h2[r][j4*4+2] = fmaf(h[r], w.z, h2[r][j4*4+2]);
                h2[r][j4*4+3] = fmaf(h[r], w.w, h2[r][j4*4+3]);
            }
        }
    }
#pragma unroll
    for (int j = 0; j < 16; ++j)
#pragma unroll
        for (int r = 0; r < R; ++r) h2[r][j] = fmaxf(h2[r][j], 0.0f);

    // ---- layer 3: pars = h2 @ W3 + b3 (W3T is (9,16)) ----
    float p[R][9];
#pragma unroll
    for (int j = 0; j < 9; ++j) {
        const float bb = sB3[j];
#pragma unroll
        for (int r = 0; r < R; ++r) p[r][j] = bb;
#pragma unroll
        for (int k4 = 0; k4 < 4; ++k4) {
            const float4 w = sW3Tv[j * 4 + k4];
#pragma unroll
            for (int r = 0; r < R; ++r) {
                p[r][j] = fmaf(h2[r][k4*4+0], w.x, p[r][j]);
                p[r][j] = fmaf(h2[r][k4*4+1], w.y, p[r][j]);
                p[r][j] = fmaf(h2[r][k4*4+2], w.z, p[r][j]);
                p[r][j] = fmaf(h2[r][k4*4+3], w.w, p[r][j]);
            }
        }
    }

    // ---- per-row epilogue ----
    float4* __restrict__ o4 = (float4*)out;
    float* __restrict__ oV = out + (size_t)n * 16;

#pragma unroll
    for (int r = 0; r < R; ++r) {
        const int row = base + 64 * r;

        const float e0 = __expf(p[r][0]);
        const float e1 = __expf(p[r][1]);
        const float e2 = __expf(p[r][2]);
        const float e3 = __expf(p[r][3]);
        const float col0 = sqrtf(e0 * e1);
        const float col1 = sqrtf(e2 * e3);
        const float rw0  = sqrtf(e0 * e2);
        const float rw1  = sqrtf(e1 * e3);
        const float corn = sqrtf(rw0 * rw1);

        const float a00 = e0,  a01 = e1,  a02 = col0;
        const float a10 = e2,  a11 = e3,  a12 = col1;
        const float a20 = rw0, a21 = rw1, a22 = corn;

        const float s4 = QLOW + QSPAN * fsig(p[r][4]);
        const float s5 = QLOW + QSPAN * fsig(p[r][5]);
        const float s6 = QLOW + QSPAN * fsig(p[r][6]);
        const float s7 = QLOW + QSPAN * fsig(p[r][7]);

        const float M0 = m[r][0], M1 = m[r][1], M2 = m[r][2];
        const float F0 = m[r][3], F1 = m[r][4], F2 = m[r][5];

        const float rm0 = M0 * s4, rm1 = M1 * s5, rm2 = M2;
        const float cm0 = F0 * s6, cm1 = F1 * s7, cm2 = F2;
        const float um0 = M0 * (1.0f - s4);
        const float um1 = M1 * (1.0f - s5);
        const float uf0 = F0 * (1.0f - s6);
        const float uf1 = F1 * (1.0f - s7);

        // Sinkhorn in scaling-vector form: A_k = diag(u) A0 diag(v)
        float u0 = 1.0f, u1 = 1.0f, u2 = 1.0f;
        float v0 = 1.0f, v1 = 1.0f, v2 = 1.0f;
#pragma unroll
        for (int it = 0; it < 10; ++it) {
            float t0 = fmaf(a02, v2, fmaf(a01, v1, a00 * v0));
            float t1 = fmaf(a12, v2, fmaf(a11, v1, a10 * v0));
            float t2 = fmaf(a22, v2, fmaf(a21, v1, a20 * v0));
            u0 = u0 * rm0 * frcp(fmaf(u0, t0, EPS_F));
            u1 = u1 * rm1 * frcp(fmaf(u1, t1, EPS_F));
            u2 = u2 * rm2 * frcp(fmaf(u2, t2, EPS_F));
            float s0 = fmaf(a20, u2, fmaf(a10, u1, a00 * u0));
            float s1 = fmaf(a21, u2, fmaf(a11, u1, a01 * u0));
            float s2 = fmaf(a22, u2, fmaf(a12, u1, a02 * u0));
            v0 = v0 * cm0 * frcp(fmaf(v0, s0, EPS_F));
            v1 = v1 * cm1 * frcp(fmaf(v1, s1, EPS_F));
            v2 = v2 * cm2 * frcp(fmaf(v2, s2, EPS_F));
        }

        const float A0f = u0 * a00 * v0, A1f = u0 * a01 * v1, A2f = u0 * a02 * v2;
        const float A3f = u1 * a10 * v0, A4f = u1 * a11 * v1, A5f = u1 * a12 * v2;
        const float A6f = u2 * a20 * v0, A7f = u2 * a21 * v1, A8f = u2 * a22 * v2;

        o4[row * 4 + 0] = make_float4(A0f, A1f, A2f, um0);
        o4[row * 4 + 1] = make_float4(A3f, A4f, A5f, um1);
        o4[row * 4 + 2] = make_float4(A6f, A7f, A8f, 0.0f);
        o4[row * 4 + 3] = make_float4(uf0, uf1, 0.0f, 0.0f);
        oV[row] = __expf(p[r][8]);
    }
}

extern "C" void kernel_launch(void* const* d_in, const int* in_sizes, int n_in,
                              void* d_out, int out_size, void* d_ws, size_t ws_size,
                              hipStream_t stream) {
    const float* margins = (const float*)d_in[0];
    const float* W1 = (const float*)d_in[1];
    const float* b1 = (const float*)d_in[2];
    const float* W2 = (const float*)d_in[3];
    const float* b2 = (const float*)d_in[4];
    const float* W3 = (const float*)d_in[5];
    const float* b3 = (const float*)d_in[6];

    const int n = in_sizes[0] / 8;       // 1,048,576 rows
    const int threads = n / R;
    dim3 block(256), grid(threads / 256);

    sinkhorn_fused<<<grid, block, 0, stream>>>(margins, W1, b1, W2, b2, W3, b3,
                                               (float*)d_out, n);
}

// Round 4
// 144.708 us; speedup vs baseline: 1.0071x; 1.0071x over previous
//
#include <hip/hip_runtime.h>
#include <math.h>

// SinkhornM round 4:
//  - Round 3 structure (R=4, fused layer1+2 output-stationary, u/v Sinkhorn)
//    with the spill fixed: __launch_bounds__(256, 3) raises the VGPR cap to
//    ~168 (round 3's default heuristic held 68 VGPRs and spilled to scratch:
//    VALUBusy 71->35%, WRITE_SIZE +2MB, dur 2x).
//  - 12 waves/CU guaranteed occupancy; DS-broadcast weights amortized over
//    4 rows/thread (~60 ds_read_b128 per row vs 114 in round 2).

#define EPS_F 1e-12f
#define QLOW  0.02f
#define QSPAN 0.96f

constexpr int R = 4;

__device__ __forceinline__ float frcp(float x) { return __builtin_amdgcn_rcpf(x); }
__device__ __forceinline__ float fsig(float x) { return frcp(1.0f + __expf(-x)); }

__global__ __launch_bounds__(256, 3) void sinkhorn_fused(
    const float* __restrict__ margins,
    const float* __restrict__ W1, const float* __restrict__ b1,
    const float* __restrict__ W2, const float* __restrict__ b2,
    const float* __restrict__ W3, const float* __restrict__ b3,
    float* __restrict__ out, int n)
{
    // ---- LDS staging ----
    __shared__ __align__(16) float sW1T[256];  // (32,8): sW1T[j*8+k] = W1[k*32+j]
    __shared__ __align__(16) float sW2[512];   // (32,16) row-major
    __shared__ __align__(16) float sW3T[144];  // (9,16):  sW3T[j*16+k] = W3[k*9+j]
    __shared__ __align__(16) float sB1[32];
    __shared__ __align__(16) float sB2[16];
    __shared__ __align__(16) float sB3[12];

    {
        const int t = threadIdx.x;
        { const int j = t >> 3, k = t & 7; sW1T[t] = W1[k * 32 + j]; }
        sW2[t] = W2[t];
        sW2[t + 256] = W2[t + 256];
        if (t < 144) { const int k = t / 9, j = t - 9 * k; sW3T[j * 16 + k] = W3[t]; }
        if (t < 32) sB1[t] = b1[t];
        if (t < 16) sB2[t] = b2[t];
        if (t < 9)  sB3[t] = b3[t];
    }
    __syncthreads();

    const float4* __restrict__ sW1Tv = (const float4*)sW1T;
    const float4* __restrict__ sW2v  = (const float4*)sW2;
    const float4* __restrict__ sW3Tv = (const float4*)sW3T;

    const int tid  = blockIdx.x * blockDim.x + threadIdx.x;
    const int lane = tid & 63;
    const int base = (tid >> 6) * (64 * R) + lane;  // rows base + 64*r

    const float4* __restrict__ m4 = (const float4*)margins;

    // ---- margins ----
    float m[R][8];
#pragma unroll
    for (int r = 0; r < R; ++r) {
        const int row = base + 64 * r;
        const float4 a0 = m4[row * 2 + 0];
        const float4 a1 = m4[row * 2 + 1];
        m[r][0] = a0.x; m[r][1] = a0.y; m[r][2] = a0.z; m[r][3] = a0.w;
        m[r][4] = a1.x; m[r][5] = a1.y; m[r][6] = a1.z; m[r][7] = a1.w;
    }

    // ---- h2 accumulators, init with bias ----
    float h2[R][16];
#pragma unroll
    for (int j = 0; j < 16; ++j) {
        const float bb = sB2[j];
#pragma unroll
        for (int r = 0; r < R; ++r) h2[r][j] = bb;
    }

    // ---- fused layer1+layer2: output-stationary over h1[j] ----
#pragma unroll
    for (int j = 0; j < 32; ++j) {
        const float4 wa = sW1Tv[j * 2 + 0];   // W1[0..3][j]
        const float4 wb = sW1Tv[j * 2 + 1];   // W1[4..7][j]
        const float bj = sB1[j];
        float h[R];
#pragma unroll
        for (int r = 0; r < R; ++r) {
            float x = bj;
            x = fmaf(m[r][0], wa.x, x);
            x = fmaf(m[r][1], wa.y, x);
            x = fmaf(m[r][2], wa.z, x);
            x = fmaf(m[r][3], wa.w, x);
            x = fmaf(m[r][4], wb.x, x);
            x = fmaf(m[r][5], wb.y, x);
            x = fmaf(m[r][6], wb.z, x);
            x = fmaf(m[r][7], wb.w, x);
            h[r] = fmaxf(x, 0.0f);
        }
#pragma unroll
        for (int j4 = 0; j4 < 4; ++j4) {
            const float4 w = sW2v[j * 4 + j4];
#pragma unroll
            for (int r = 0; r < R; ++r) {
                h2[r][j4*4+0] = fmaf(h[r], w.x, h2[r][j4*4+0]);
                h2[r][j4*4+1] = fmaf(h[r], w.y, h2[r][j4*4+1]);
                h2[r][j4*4+2] = fmaf(h[r], w.z, h2[r][j4*4+2]);
                h2[r][j4*4+3] = fmaf(h[r], w.w, h2[r][j4*4+3]);
            }
        }
    }
#pragma unroll
    for (int j = 0; j < 16; ++j)
#pragma unroll
        for (int r = 0; r < R; ++r) h2[r][j] = fmaxf(h2[r][j], 0.0f);

    // ---- layer 3: pars = h2 @ W3 + b3 (W3T is (9,16)) ----
    float p[R][9];
#pragma unroll
    for (int j = 0; j < 9; ++j) {
        const float bb = sB3[j];
#pragma unroll
        for (int r = 0; r < R; ++r) p[r][j] = bb;
#pragma unroll
        for (int k4 = 0; k4 < 4; ++k4) {
            const float4 w = sW3Tv[j * 4 + k4];
#pragma unroll
            for (int r = 0; r < R; ++r) {
                p[r][j] = fmaf(h2[r][k4*4+0], w.x, p[r][j]);
                p[r][j] = fmaf(h2[r][k4*4+1], w.y, p[r][j]);
                p[r][j] = fmaf(h2[r][k4*4+2], w.z, p[r][j]);
                p[r][j] = fmaf(h2[r][k4*4+3], w.w, p[r][j]);
            }
        }
    }

    // ---- per-row epilogue ----
    float4* __restrict__ o4 = (float4*)out;
    float* __restrict__ oV = out + (size_t)n * 16;

#pragma unroll
    for (int r = 0; r < R; ++r) {
        const int row = base + 64 * r;

        const float e0 = __expf(p[r][0]);
        const float e1 = __expf(p[r][1]);
        const float e2 = __expf(p[r][2]);
        const float e3 = __expf(p[r][3]);
        const float col0 = sqrtf(e0 * e1);
        const float col1 = sqrtf(e2 * e3);
        const float rw0  = sqrtf(e0 * e2);
        const float rw1  = sqrtf(e1 * e3);
        const float corn = sqrtf(rw0 * rw1);

        const float a00 = e0,  a01 = e1,  a02 = col0;
        const float a10 = e2,  a11 = e3,  a12 = col1;
        const float a20 = rw0, a21 = rw1, a22 = corn;

        const float s4 = QLOW + QSPAN * fsig(p[r][4]);
        const float s5 = QLOW + QSPAN * fsig(p[r][5]);
        const float s6 = QLOW + QSPAN * fsig(p[r][6]);
        const float s7 = QLOW + QSPAN * fsig(p[r][7]);

        const float M0 = m[r][0], M1 = m[r][1], M2 = m[r][2];
        const float F0 = m[r][3], F1 = m[r][4], F2 = m[r][5];

        const float rm0 = M0 * s4, rm1 = M1 * s5, rm2 = M2;
        const float cm0 = F0 * s6, cm1 = F1 * s7, cm2 = F2;
        const float um0 = M0 * (1.0f - s4);
        const float um1 = M1 * (1.0f - s5);
        const float uf0 = F0 * (1.0f - s6);
        const float uf1 = F1 * (1.0f - s7);

        // Sinkhorn in scaling-vector form: A_k = diag(u) A0 diag(v)
        float u0 = 1.0f, u1 = 1.0f, u2 = 1.0f;
        float v0 = 1.0f, v1 = 1.0f, v2 = 1.0f;
#pragma unroll
        for (int it = 0; it < 10; ++it) {
            float t0 = fmaf(a02, v2, fmaf(a01, v1, a00 * v0));
            float t1 = fmaf(a12, v2, fmaf(a11, v1, a10 * v0));
            float t2 = fmaf(a22, v2, fmaf(a21, v1, a20 * v0));
            u0 = u0 * rm0 * frcp(fmaf(u0, t0, EPS_F));
            u1 = u1 * rm1 * frcp(fmaf(u1, t1, EPS_F));
            u2 = u2 * rm2 * frcp(fmaf(u2, t2, EPS_F));
            float s0 = fmaf(a20, u2, fmaf(a10, u1, a00 * u0));
            float s1 = fmaf(a21, u2, fmaf(a11, u1, a01 * u0));
            float s2 = fmaf(a22, u2, fmaf(a12, u1, a02 * u0));
            v0 = v0 * cm0 * frcp(fmaf(v0, s0, EPS_F));
            v1 = v1 * cm1 * frcp(fmaf(v1, s1, EPS_F));
            v2 = v2 * cm2 * frcp(fmaf(v2, s2, EPS_F));
        }

        const float A0f = u0 * a00 * v0, A1f = u0 * a01 * v1, A2f = u0 * a02 * v2;
        const float A3f = u1 * a10 * v0, A4f = u1 * a11 * v1, A5f = u1 * a12 * v2;
        const float A6f = u2 * a20 * v0, A7f = u2 * a21 * v1, A8f = u2 * a22 * v2;

        o4[row * 4 + 0] = make_float4(A0f, A1f, A2f, um0);
        o4[row * 4 + 1] = make_float4(A3f, A4f, A5f, um1);
        o4[row * 4 + 2] = make_float4(A6f, A7f, A8f, 0.0f);
        o4[row * 4 + 3] = make_float4(uf0, uf1, 0.0f, 0.0f);
        oV[row] = __expf(p[r][8]);
    }
}

extern "C" void kernel_launch(void* const* d_in, const int* in_sizes, int n_in,
                              void* d_out, int out_size, void* d_ws, size_t ws_size,
                              hipStream_t stream) {
    const float* margins = (const float*)d_in[0];
    const float* W1 = (const float*)d_in[1];
    const float* b1 = (const float*)d_in[2];
    const float* W2 = (const float*)d_in[3];
    const float* b2 = (const float*)d_in[4];
    const float* W3 = (const float*)d_in[5];
    const float* b3 = (const float*)d_in[6];

    const int n = in_sizes[0] / 8;       // 1,048,576 rows
    const int threads = n / R;
    dim3 block(256), grid(threads / 256);

    sinkhorn_fused<<<grid, block, 0, stream>>>(margins, W1, b1, W2, b2, W3, b3,
                                               (float*)d_out, n);
}

// Round 5
// 140.042 us; speedup vs baseline: 1.0407x; 1.0333x over previous
//
#include <hip/hip_runtime.h>
#include <math.h>

// SinkhornM round 5:
//  - Root cause of r3/r4: private arrays m[4][8]/h2[4][16]/p[4][9] were never
//    promoted to VGPRs (VGPR_Count frozen at 68 across different launch_bounds,
//    variable scratch WRITE traffic) -> every access went to scratch memory.
//  - Fix: NO C arrays. All per-row state is ext_vector_type SSA values
//    (float8 m0..m3, float16 acc0..acc3) + named scalars p0..p8 in a
//    force-inlined per-row epilogue. The backend must register-allocate SSA.
//  - __launch_bounds__(256,4): VGPR cap 128, 4 waves/SIMD, grid 1024 blocks
//    = exactly 4 blocks/CU (no occupancy tail).
//  - R=4 keeps the halved LDS-pipe cost (~68 ds_read per row vs 114 at R=2).
//  - __builtin_amdgcn_sqrtf replaces sqrtf (no IEEE fixup sequence).

#define EPS_F 1e-12f
#define QLOW  0.02f
#define QSPAN 0.96f

typedef float vf8  __attribute__((ext_vector_type(8)));
typedef float vf16 __attribute__((ext_vector_type(16)));

__device__ __forceinline__ float frcp(float x)  { return __builtin_amdgcn_rcpf(x); }
__device__ __forceinline__ float fsqrtf(float x){ return __builtin_amdgcn_sqrtf(x); }
__device__ __forceinline__ float fsig(float x)  { return frcp(1.0f + __expf(-x)); }

__device__ __forceinline__ void do_row(
    vf16 a, vf8 mr, int row,
    const float4* __restrict__ sW3Tv, const float* __restrict__ sB3,
    float4* __restrict__ o4, float* __restrict__ oV)
{
    // ---- layer 3: p = relu(a) @ W3 + b3, W3T is (9,16) ----
#define P_DECL(j) float p##j = sB3[j];
    P_DECL(0) P_DECL(1) P_DECL(2) P_DECL(3) P_DECL(4)
    P_DECL(5) P_DECL(6) P_DECL(7) P_DECL(8)
#undef P_DECL
#pragma unroll
    for (int k4 = 0; k4 < 4; ++k4) {
        const float a0 = a[k4*4+0], a1 = a[k4*4+1];
        const float a2 = a[k4*4+2], a3 = a[k4*4+3];
#define L3(j) { const float4 w = sW3Tv[j*4 + k4]; \
                p##j = fmaf(a3, w.w, fmaf(a2, w.z, fmaf(a1, w.y, fmaf(a0, w.x, p##j)))); }
        L3(0) L3(1) L3(2) L3(3) L3(4) L3(5) L3(6) L3(7) L3(8)
#undef L3
    }

    // ---- tau(exp(p0..p3)) ----
    const float e0 = __expf(p0);
    const float e1 = __expf(p1);
    const float e2 = __expf(p2);
    const float e3 = __expf(p3);
    const float col0 = fsqrtf(e0 * e1);
    const float col1 = fsqrtf(e2 * e3);
    const float rw0  = fsqrtf(e0 * e2);
    const float rw1  = fsqrtf(e1 * e3);
    const float corn = fsqrtf(rw0 * rw1);

    const float a00 = e0,  a01 = e1,  a02 = col0;
    const float a10 = e2,  a11 = e3,  a12 = col1;
    const float a20 = rw0, a21 = rw1, a22 = corn;

    // ---- shares ----
    const float s4 = QLOW + QSPAN * fsig(p4);
    const float s5 = QLOW + QSPAN * fsig(p5);
    const float s6 = QLOW + QSPAN * fsig(p6);
    const float s7 = QLOW + QSPAN * fsig(p7);

    const float M0 = mr[0], M1 = mr[1], M2 = mr[2];
    const float F0 = mr[3], F1 = mr[4], F2 = mr[5];

    const float rm0 = M0 * s4, rm1 = M1 * s5, rm2 = M2;
    const float cm0 = F0 * s6, cm1 = F1 * s7, cm2 = F2;
    const float um0 = M0 * (1.0f - s4);
    const float um1 = M1 * (1.0f - s5);
    const float uf0 = F0 * (1.0f - s6);
    const float uf1 = F1 * (1.0f - s7);

    // ---- Sinkhorn, scaling-vector form: A_k = diag(u) A0 diag(v) ----
    float u0 = 1.0f, u1 = 1.0f, u2 = 1.0f;
    float v0 = 1.0f, v1 = 1.0f, v2 = 1.0f;
#pragma unroll
    for (int it = 0; it < 10; ++it) {
        float t0 = fmaf(a02, v2, fmaf(a01, v1, a00 * v0));
        float t1 = fmaf(a12, v2, fmaf(a11, v1, a10 * v0));
        float t2 = fmaf(a22, v2, fmaf(a21, v1, a20 * v0));
        u0 = u0 * rm0 * frcp(fmaf(u0, t0, EPS_F));
        u1 = u1 * rm1 * frcp(fmaf(u1, t1, EPS_F));
        u2 = u2 * rm2 * frcp(fmaf(u2, t2, EPS_F));
        float s0 = fmaf(a20, u2, fmaf(a10, u1, a00 * u0));
        float s1 = fmaf(a21, u2, fmaf(a11, u1, a01 * u0));
        float s2 = fmaf(a22, u2, fmaf(a12, u1, a02 * u0));
        v0 = v0 * cm0 * frcp(fmaf(v0, s0, EPS_F));
        v1 = v1 * cm1 * frcp(fmaf(v1, s1, EPS_F));
        v2 = v2 * cm2 * frcp(fmaf(v2, s2, EPS_F));
    }

    const float A0f = u0 * a00 * v0, A1f = u0 * a01 * v1, A2f = u0 * a02 * v2;
    const float A3f = u1 * a10 * v0, A4f = u1 * a11 * v1, A5f = u1 * a12 * v2;
    const float A6f = u2 * a20 * v0, A7f = u2 * a21 * v1, A8f = u2 * a22 * v2;

    o4[row * 4 + 0] = make_float4(A0f, A1f, A2f, um0);
    o4[row * 4 + 1] = make_float4(A3f, A4f, A5f, um1);
    o4[row * 4 + 2] = make_float4(A6f, A7f, A8f, 0.0f);
    o4[row * 4 + 3] = make_float4(uf0, uf1, 0.0f, 0.0f);
    oV[row] = __expf(p8);
}

__global__ __launch_bounds__(256, 4) void sinkhorn_fused(
    const float* __restrict__ margins,
    const float* __restrict__ W1, const float* __restrict__ b1,
    const float* __restrict__ W2, const float* __restrict__ b2,
    const float* __restrict__ W3, const float* __restrict__ b3,
    float* __restrict__ out, int n)
{
    // ---- LDS staging ----
    __shared__ __align__(16) float sW1T[256];  // (32,8): sW1T[j*8+k] = W1[k*32+j]
    __shared__ __align__(16) float sW2[512];   // (32,16) row-major
    __shared__ __align__(16) float sW3T[144];  // (9,16):  sW3T[j*16+k] = W3[k*9+j]
    __shared__ __align__(16) float sB1[32];
    __shared__ __align__(16) float sB2[16];
    __shared__ __align__(16) float sB3[12];

    {
        const int t = threadIdx.x;
        { const int j = t >> 3, k = t & 7; sW1T[t] = W1[k * 32 + j]; }
        sW2[t] = W2[t];
        sW2[t + 256] = W2[t + 256];
        if (t < 144) { const int k = t / 9, j = t - 9 * k; sW3T[j * 16 + k] = W3[t]; }
        if (t < 32) sB1[t] = b1[t];
        if (t < 16) sB2[t] = b2[t];
        if (t < 9)  sB3[t] = b3[t];
    }
    __syncthreads();

    const float4* __restrict__ sW1Tv = (const float4*)sW1T;
    const float4* __restrict__ sW2v  = (const float4*)sW2;
    const float4* __restrict__ sW3Tv = (const float4*)sW3T;

    const int tid  = blockIdx.x * blockDim.x + threadIdx.x;
    const int lane = tid & 63;
    const int base = (tid >> 6) * 256 + lane;   // rows: base + 64*r, r=0..3

    const vf8* __restrict__ m8 = (const vf8*)margins;

#define ROWS(X) X(0) X(1) X(2) X(3)

    // ---- margins as SSA float8 ----
#define LOADM(r) vf8 m##r = m8[base + 64*r];
    ROWS(LOADM)
#undef LOADM

    // ---- h2 accumulators (SSA float16), init with b2 ----
    vf16 binit;
#pragma unroll
    for (int j = 0; j < 16; ++j) binit[j] = sB2[j];
#define INITA(r) vf16 acc##r = binit;
    ROWS(INITA)
#undef INITA

    // ---- fused layer1+layer2, output-stationary over h1[j] ----
#pragma unroll
    for (int j = 0; j < 32; ++j) {
        const float4 wa = sW1Tv[j * 2 + 0];
        const float4 wb = sW1Tv[j * 2 + 1];
        const float bj = sB1[j];
#define L1(r) float h_##r = fmaf(m##r[7], wb.w, fmaf(m##r[6], wb.z, \
                fmaf(m##r[5], wb.y, fmaf(m##r[4], wb.x, \
                fmaf(m##r[3], wa.w, fmaf(m##r[2], wa.z, \
                fmaf(m##r[1], wa.y, fmaf(m##r[0], wa.x, bj)))))))); \
              h_##r = fmaxf(h_##r, 0.0f);
        ROWS(L1)
#undef L1
#pragma unroll
        for (int j4 = 0; j4 < 4; ++j4) {
            const float4 w = sW2v[j * 4 + j4];
#define L2(r) acc##r[j4*4+0] = fmaf(h_##r, w.x, acc##r[j4*4+0]); \
              acc##r[j4*4+1] = fmaf(h_##r, w.y, acc##r[j4*4+1]); \
              acc##r[j4*4+2] = fmaf(h_##r, w.z, acc##r[j4*4+2]); \
              acc##r[j4*4+3] = fmaf(h_##r, w.w, acc##r[j4*4+3]);
            ROWS(L2)
#undef L2
        }
    }

    // ---- ReLU on h2 ----
#define RELU(r) _Pragma("unroll") \
    for (int j = 0; j < 16; ++j) acc##r[j] = fmaxf(acc##r[j], 0.0f);
    ROWS(RELU)
#undef RELU

    // ---- per-row layer3 + tau + sinkhorn + store ----
    float4* __restrict__ o4 = (float4*)out;
    float*  __restrict__ oV = out + (size_t)n * 16;

#define EPI(r) do_row(acc##r, m##r, base + 64*r, sW3Tv, sB3, o4, oV);
    ROWS(EPI)
#undef EPI
#undef ROWS
}

extern "C" void kernel_launch(void* const* d_in, const int* in_sizes, int n_in,
                              void* d_out, int out_size, void* d_ws, size_t ws_size,
                              hipStream_t stream) {
    const float* margins = (const float*)d_in[0];
    const float* W1 = (const float*)d_in[1];
    const float* b1 = (const float*)d_in[2];
    const float* W2 = (const float*)d_in[3];
    const float* b2 = (const float*)d_in[4];
    const float* W3 = (const float*)d_in[5];
    const float* b3 = (const float*)d_in[6];

    const int n = in_sizes[0] / 8;        // 1,048,576 rows
    const int threads = n / 4;            // R = 4 rows/thread
    dim3 block(256), grid(threads / 256); // 1024 blocks = 4 blocks/CU

    sinkhorn_fused<<<grid, block, 0, stream>>>(margins, W1, b1, W2, b2, W3, b3,
                                               (float*)d_out, n);
}

// Round 6
// 137.560 us; speedup vs baseline: 1.0595x; 1.0180x over previous
//
#include <hip/hip_runtime.h>
#include <math.h>

// SinkhornM round 6:
//  - r3/r4/r5 showed the RA pressure-targets 64-68 VGPRs and spills the R=4
//    live set regardless of __launch_bounds__ (which only sets MIN waves/EU;
//    the scheduler still chases its default MAX occupancy target).
//  - Fix under test: amdgpu_waves_per_eu(2,4) caps the MAX at 4 waves/EU ->
//    scheduler pressure target >=128 VGPRs, budget up to 256. Fused R=4
//    live set (~115-135 floats) should finally stay in registers.
//  - Everything else = round 5: SSA ext_vector state, fused layer1+2
//    output-stationary, u/v-form Sinkhorn, W3 transposed, native sqrt/rcp.

#define EPS_F 1e-12f
#define QLOW  0.02f
#define QSPAN 0.96f

typedef float vf8  __attribute__((ext_vector_type(8)));
typedef float vf16 __attribute__((ext_vector_type(16)));

__device__ __forceinline__ float frcp(float x)  { return __builtin_amdgcn_rcpf(x); }
__device__ __forceinline__ float fsqrtf(float x){ return __builtin_amdgcn_sqrtf(x); }
__device__ __forceinline__ float fsig(float x)  { return frcp(1.0f + __expf(-x)); }

__device__ __forceinline__ void do_row(
    vf16 a, vf8 mr, int row,
    const float4* __restrict__ sW3Tv, const float* __restrict__ sB3,
    float4* __restrict__ o4, float* __restrict__ oV)
{
    // ---- layer 3: p = a @ W3 + b3, W3T is (9,16) ----
#define P_DECL(j) float p##j = sB3[j];
    P_DECL(0) P_DECL(1) P_DECL(2) P_DECL(3) P_DECL(4)
    P_DECL(5) P_DECL(6) P_DECL(7) P_DECL(8)
#undef P_DECL
#pragma unroll
    for (int k4 = 0; k4 < 4; ++k4) {
        const float a0 = a[k4*4+0], a1 = a[k4*4+1];
        const float a2 = a[k4*4+2], a3 = a[k4*4+3];
#define L3(j) { const float4 w = sW3Tv[j*4 + k4]; \
                p##j = fmaf(a3, w.w, fmaf(a2, w.z, fmaf(a1, w.y, fmaf(a0, w.x, p##j)))); }
        L3(0) L3(1) L3(2) L3(3) L3(4) L3(5) L3(6) L3(7) L3(8)
#undef L3
    }

    // ---- tau(exp(p0..p3)) ----
    const float e0 = __expf(p0);
    const float e1 = __expf(p1);
    const float e2 = __expf(p2);
    const float e3 = __expf(p3);
    const float col0 = fsqrtf(e0 * e1);
    const float col1 = fsqrtf(e2 * e3);
    const float rw0  = fsqrtf(e0 * e2);
    const float rw1  = fsqrtf(e1 * e3);
    const float corn = fsqrtf(rw0 * rw1);

    const float a00 = e0,  a01 = e1,  a02 = col0;
    const float a10 = e2,  a11 = e3,  a12 = col1;
    const float a20 = rw0, a21 = rw1, a22 = corn;

    // ---- shares ----
    const float s4 = QLOW + QSPAN * fsig(p4);
    const float s5 = QLOW + QSPAN * fsig(p5);
    const float s6 = QLOW + QSPAN * fsig(p6);
    const float s7 = QLOW + QSPAN * fsig(p7);

    const float M0 = mr[0], M1 = mr[1], M2 = mr[2];
    const float F0 = mr[3], F1 = mr[4], F2 = mr[5];

    const float rm0 = M0 * s4, rm1 = M1 * s5, rm2 = M2;
    const float cm0 = F0 * s6, cm1 = F1 * s7, cm2 = F2;
    const float um0 = M0 * (1.0f - s4);
    const float um1 = M1 * (1.0f - s5);
    const float uf0 = F0 * (1.0f - s6);
    const float uf1 = F1 * (1.0f - s7);

    // ---- Sinkhorn, scaling-vector form: A_k = diag(u) A0 diag(v) ----
    float u0 = 1.0f, u1 = 1.0f, u2 = 1.0f;
    float v0 = 1.0f, v1 = 1.0f, v2 = 1.0f;
#pragma unroll
    for (int it = 0; it < 10; ++it) {
        float t0 = fmaf(a02, v2, fmaf(a01, v1, a00 * v0));
        float t1 = fmaf(a12, v2, fmaf(a11, v1, a10 * v0));
        float t2 = fmaf(a22, v2, fmaf(a21, v1, a20 * v0));
        u0 = u0 * rm0 * frcp(fmaf(u0, t0, EPS_F));
        u1 = u1 * rm1 * frcp(fmaf(u1, t1, EPS_F));
        u2 = u2 * rm2 * frcp(fmaf(u2, t2, EPS_F));
        float s0 = fmaf(a20, u2, fmaf(a10, u1, a00 * u0));
        float s1 = fmaf(a21, u2, fmaf(a11, u1, a01 * u0));
        float s2 = fmaf(a22, u2, fmaf(a12, u1, a02 * u0));
        v0 = v0 * cm0 * frcp(fmaf(v0, s0, EPS_F));
        v1 = v1 * cm1 * frcp(fmaf(v1, s1, EPS_F));
        v2 = v2 * cm2 * frcp(fmaf(v2, s2, EPS_F));
    }

    const float A0f = u0 * a00 * v0, A1f = u0 * a01 * v1, A2f = u0 * a02 * v2;
    const float A3f = u1 * a10 * v0, A4f = u1 * a11 * v1, A5f = u1 * a12 * v2;
    const float A6f = u2 * a20 * v0, A7f = u2 * a21 * v1, A8f = u2 * a22 * v2;

    o4[row * 4 + 0] = make_float4(A0f, A1f, A2f, um0);
    o4[row * 4 + 1] = make_float4(A3f, A4f, A5f, um1);
    o4[row * 4 + 2] = make_float4(A6f, A7f, A8f, 0.0f);
    o4[row * 4 + 3] = make_float4(uf0, uf1, 0.0f, 0.0f);
    oV[row] = __expf(p8);
}

__global__ void
__attribute__((amdgpu_flat_work_group_size(256, 256), amdgpu_waves_per_eu(2, 4)))
sinkhorn_fused(
    const float* __restrict__ margins,
    const float* __restrict__ W1, const float* __restrict__ b1,
    const float* __restrict__ W2, const float* __restrict__ b2,
    const float* __restrict__ W3, const float* __restrict__ b3,
    float* __restrict__ out, int n)
{
    // ---- LDS staging ----
    __shared__ __align__(16) float sW1T[256];  // (32,8): sW1T[j*8+k] = W1[k*32+j]
    __shared__ __align__(16) float sW2[512];   // (32,16) row-major
    __shared__ __align__(16) float sW3T[144];  // (9,16):  sW3T[j*16+k] = W3[k*9+j]
    __shared__ __align__(16) float sB1[32];
    __shared__ __align__(16) float sB2[16];
    __shared__ __align__(16) float sB3[12];

    {
        const int t = threadIdx.x;
        { const int j = t >> 3, k = t & 7; sW1T[t] = W1[k * 32 + j]; }
        sW2[t] = W2[t];
        sW2[t + 256] = W2[t + 256];
        if (t < 144) { const int k = t / 9, j = t - 9 * k; sW3T[j * 16 + k] = W3[t]; }
        if (t < 32) sB1[t] = b1[t];
        if (t < 16) sB2[t] = b2[t];
        if (t < 9)  sB3[t] = b3[t];
    }
    __syncthreads();

    const float4* __restrict__ sW1Tv = (const float4*)sW1T;
    const float4* __restrict__ sW2v  = (const float4*)sW2;
    const float4* __restrict__ sW3Tv = (const float4*)sW3T;

    const int tid  = blockIdx.x * blockDim.x + threadIdx.x;
    const int lane = tid & 63;
    const int base = (tid >> 6) * 256 + lane;   // rows: base + 64*r, r=0..3

    const vf8* __restrict__ m8 = (const vf8*)margins;

#define ROWS(X) X(0) X(1) X(2) X(3)

    // ---- margins as SSA float8 ----
#define LOADM(r) vf8 m##r = m8[base + 64*r];
    ROWS(LOADM)
#undef LOADM

    // ---- h2 accumulators (SSA float16), init with b2 ----
    vf16 binit;
#pragma unroll
    for (int j = 0; j < 16; ++j) binit[j] = sB2[j];
#define INITA(r) vf16 acc##r = binit;
    ROWS(INITA)
#undef INITA

    // ---- fused layer1+layer2, output-stationary over h1[j] ----
#pragma unroll
    for (int j = 0; j < 32; ++j) {
        const float4 wa = sW1Tv[j * 2 + 0];
        const float4 wb = sW1Tv[j * 2 + 1];
        const float bj = sB1[j];
#define L1(r) float h_##r = fmaf(m##r[7], wb.w, fmaf(m##r[6], wb.z, \
                fmaf(m##r[5], wb.y, fmaf(m##r[4], wb.x, \
                fmaf(m##r[3], wa.w, fmaf(m##r[2], wa.z, \
                fmaf(m##r[1], wa.y, fmaf(m##r[0], wa.x, bj)))))))); \
              h_##r = fmaxf(h_##r, 0.0f);
        ROWS(L1)
#undef L1
#pragma unroll
        for (int j4 = 0; j4 < 4; ++j4) {
            const float4 w = sW2v[j * 4 + j4];
#define L2(r) acc##r[j4*4+0] = fmaf(h_##r, w.x, acc##r[j4*4+0]); \
              acc##r[j4*4+1] = fmaf(h_##r, w.y, acc##r[j4*4+1]); \
              acc##r[j4*4+2] = fmaf(h_##r, w.z, acc##r[j4*4+2]); \
              acc##r[j4*4+3] = fmaf(h_##r, w.w, acc##r[j4*4+3]);
            ROWS(L2)
#undef L2
        }
    }

    // ---- ReLU on h2 ----
#define RELU(r) _Pragma("unroll") \
    for (int j = 0; j < 16; ++j) acc##r[j] = fmaxf(acc##r[j], 0.0f);
    ROWS(RELU)
#undef RELU

    // ---- per-row layer3 + tau + sinkhorn + store ----
    float4* __restrict__ o4 = (float4*)out;
    float*  __restrict__ oV = out + (size_t)n * 16;

#define EPI(r) do_row(acc##r, m##r, base + 64*r, sW3Tv, sB3, o4, oV);
    ROWS(EPI)
#undef EPI
#undef ROWS
}

extern "C" void kernel_launch(void* const* d_in, const int* in_sizes, int n_in,
                              void* d_out, int out_size, void* d_ws, size_t ws_size,
                              hipStream_t stream) {
    const float* margins = (const float*)d_in[0];
    const float* W1 = (const float*)d_in[1];
    const float* b1 = (const float*)d_in[2];
    const float* W2 = (const float*)d_in[3];
    const float* b2 = (const float*)d_in[4];
    const float* W3 = (const float*)d_in[5];
    const float* b3 = (const float*)d_in[6];

    const int n = in_sizes[0] / 8;        // 1,048,576 rows
    const int threads = n / 4;            // R = 4 rows/thread
    dim3 block(256), grid(threads / 256); // 1024 blocks = 4 blocks/CU

    sinkhorn_fused<<<grid, block, 0, stream>>>(margins, W1, b1, W2, b2, W3, b3,
                                               (float*)d_out, n);
}